// Round 7
// baseline (210.957 us; speedup 1.0000x reference)
//
#include <hip/hip_runtime.h>
#include <hip/hip_bf16.h>
#include <stdint.h>

// MHA fwd, B=4 T=2048 D=768 H=12 HD=64, fp32 io, NO mask, scale=1/8.
// R7: qkv+out GEMMs BK=64 (half the barrier drains); cast+prep merged (4 launches).
// attn frozen from R5 (65 us).

#define HH   12
#define TT   2048
#define DIN  768
#define DOUT 768
#define HD   64
#define BB   4
#define MTOT (BB*TT)      // 8192
#define NQKV (3*DOUT)     // 2304
#define QSCALE 0.1803368801111832f   // 0.125 * log2(e)

typedef float  float4v  __attribute__((ext_vector_type(4)));
typedef float  float16v __attribute__((ext_vector_type(16)));
typedef __bf16 bf16x8   __attribute__((ext_vector_type(8)));
typedef short  short8v  __attribute__((ext_vector_type(8)));

#define AS1 __attribute__((address_space(1)))
#define AS3 __attribute__((address_space(3)))

static __device__ __forceinline__ void gload_lds16(const void* g, void* l) {
    __builtin_amdgcn_global_load_lds((AS1 void*)g, (AS3 void*)l, 16, 0, 0);
}

static __device__ __forceinline__ short f2bf(float f) {
    __bf16 h = (__bf16)f;
    return __builtin_bit_cast(short, h);
}

// ---- merged prep: bz<4 = weight transpose tiles; bz==4 = cast x -> bf16 ----
__global__ __launch_bounds__(256) void prep_kernel(const float* __restrict__ x,
                                                   const float* __restrict__ Wq,
                                                   const float* __restrict__ Wk,
                                                   const float* __restrict__ Wv,
                                                   const float* __restrict__ Wo,
                                                   short* __restrict__ Xb,
                                                   short* __restrict__ Wqkvt,
                                                   short* __restrict__ Wot) {
    __shared__ short tile[32 * 33];
    const int bx = blockIdx.x, by = blockIdx.y, bz = blockIdx.z;
    if (bz == 4) {
        const int n4 = MTOT * DIN / 4;
        const int base = (by * 24 + bx) * 256 + threadIdx.x;
        for (int i = base; i < n4; i += 24 * 24 * 256) {
            float4 v = ((const float4*)x)[i];
            short4 o;
            o.x = f2bf(v.x); o.y = f2bf(v.y); o.z = f2bf(v.z); o.w = f2bf(v.w);
            ((short4*)Xb)[i] = o;
        }
        return;
    }
    const float* W = (bz == 0) ? Wq : (bz == 1) ? Wk : (bz == 2) ? Wv : Wo;
    const int tx = threadIdx.x & 31, ty = threadIdx.x >> 5;
    for (int i = 0; i < 4; i++) {
        int k = by * 32 + ty + i * 8;
        tile[(ty + i * 8) * 33 + tx] = f2bf(W[(size_t)k * DOUT + bx * 32 + tx]);
    }
    __syncthreads();
    for (int i = 0; i < 4; i++) {
        int n = bx * 32 + ty + i * 8;
        int k = by * 32 + tx;
        short v = tile[tx * 33 + ty + i * 8];
        if (bz < 3) Wqkvt[(size_t)(bz * DOUT + n) * DIN + k] = v;
        else        Wot[(size_t)n * DOUT + k] = v;
    }
}

// ---- QKV GEMM: C[8192][2304] = Xb @ Wqkvt^T ; BK=64, 12 iters ----
__global__ __launch_bounds__(256) void qkv_gemm_kernel(const short* __restrict__ Xb,
                                                       const short* __restrict__ Wt,
                                                       short* __restrict__ Qb,
                                                       short* __restrict__ Kb,
                                                       short* __restrict__ Vt) {
    __shared__ __align__(16) short lds[16384];   // GEMM: A 16KB | B 16KB; epilogue reuses 32KB
    short* ldsA = lds;
    short* ldsB = lds + 8192;
    const int t = threadIdx.x;
    const int w = t >> 6, lane = t & 63;
    const int quad = lane >> 4, l15 = lane & 15;
    const int m0 = blockIdx.x * 128, n0 = blockIdx.y * 128;
    const int wm = (w >> 1) * 64, wn = (w & 1) * 64;

    float4v acc[4][4];
    for (int i = 0; i < 4; i++)
        for (int j = 0; j < 4; j++)
            acc[i][j] = (float4v)0.0f;

    // staging: 128 rows x 8 chunks(16B) per tile; thread t -> slots t+256g
    int sOff[4];   // global column offset (shorts) per slot, swizzled
    int sRow[4];
#pragma unroll
    for (int g = 0; g < 4; g++) {
        int slot = g * 256 + t;
        int row = slot >> 3, ch = slot & 7;
        sRow[g] = row;
        sOff[g] = ((ch ^ (row & 7)) * 8);
    }
    const int pos_r = 0;  // (placeholder to keep diffs small)

    for (int k0 = 0; k0 < DIN; k0 += 64) {
#pragma unroll
        for (int g = 0; g < 4; g++)
            gload_lds16(Xb + (size_t)(m0 + sRow[g]) * DIN + k0 + sOff[g], &ldsA[(g * 256 + t) * 8]);
#pragma unroll
        for (int g = 0; g < 4; g++)
            gload_lds16(Wt + (size_t)(n0 + sRow[g]) * DIN + k0 + sOff[g], &ldsB[(g * 256 + t) * 8]);
        __syncthreads();
#pragma unroll
        for (int f = 0; f < 2; f++) {
            bf16x8 af[4], bfr[4];
            for (int i = 0; i < 4; i++) {
                int row = wm + i * 16 + l15;
                af[i] = *(const bf16x8*)&ldsA[row * 64 + (((f * 4 + quad) ^ (row & 7)) * 8)];
            }
            for (int j = 0; j < 4; j++) {
                int row = wn + j * 16 + l15;
                bfr[j] = *(const bf16x8*)&ldsB[row * 64 + (((f * 4 + quad) ^ (row & 7)) * 8)];
            }
            for (int i = 0; i < 4; i++)
                for (int j = 0; j < 4; j++)
                    acc[i][j] = __builtin_amdgcn_mfma_f32_16x16x32_bf16(af[i], bfr[j], acc[i][j], 0, 0, 0);
        }
        __syncthreads();
    }
    (void)pos_r;

    const int which = n0 / DOUT;
    if (which < 2) {
        // Q/K epilogue: single-pass 128x128 LDS tile, 1 barrier, b128 stores.
        short* ldsT = lds;   // 128 x 128 shorts = 32 KB
        const float sc = (which == 0) ? QSCALE : 1.0f;
        short* dst = (which == 0) ? Qb : Kb;
        const int n0sec = n0 - which * DOUT;
        for (int i = 0; i < 4; i++)
            for (int j = 0; j < 4; j++) {
                int col = wn + j * 16 + l15;
                int cx = col >> 3, co = col & 7;
                for (int r = 0; r < 4; r++) {
                    int row = wm + i * 16 + quad * 4 + r;
                    ldsT[row * 128 + ((cx ^ (row & 7)) * 8 + co)] = f2bf(acc[i][j][r] * sc);
                }
            }
        __syncthreads();
        for (int p = 0; p < 8; p++) {
            int row = p * 16 + (t >> 4);
            int cL = t & 15;
            short8v v = *(const short8v*)&ldsT[row * 128 + ((cL ^ (row & 7)) * 8)];
            int mg = m0 + row;
            int b2 = mg >> 11, tq = mg & 2047;
            int colg = n0sec + cL * 8;
            int hh = colg >> 6, d = colg & 63;
            *(short8v*)&dst[((size_t)((b2 * HH + hh) * TT + tq) << 6) + d] = v;
        }
    } else {
        // V epilogue: single-pass transpose 128(d) x 128(t) LDS tile, b128 stores.
        short* ldsT = lds;
        const int n0r = n0 - 2 * DOUT;
        const int b = m0 >> 11, tq0 = m0 & 2047;
        for (int i = 0; i < 4; i++)
            for (int j = 0; j < 4; j++)
                for (int r = 0; r < 4; r++) {
                    int nl = wn + j * 16 + l15;
                    int ml = wm + i * 16 + quad * 4 + r;
                    int c = ml >> 3, o = ml & 7;
                    ldsT[nl * 128 + ((c ^ (nl & 7)) * 8 + o)] = f2bf(acc[i][j][r]);
                }
        __syncthreads();
        for (int p = 0; p < 8; p++) {
            int nrow = p * 16 + (t >> 4);
            int cc = t & 15;
            short8v v = *(const short8v*)&ldsT[nrow * 128 + ((cc ^ (nrow & 7)) * 8)];
            int colg = n0r + nrow;
            int hh = colg >> 6, d = colg & 63;
            *(short8v*)&Vt[(size_t)((b * HH + hh) * HD + d) * TT + tq0 + cc * 8] = v;
        }
    }
}

// ---- Flash attention (frozen from R5): 32x32x16, K-row-permuted, P in regs ----
__global__ __launch_bounds__(256, 3) void attn_kernel(const short* __restrict__ Qb,
                                                      const short* __restrict__ Kb,
                                                      const short* __restrict__ Vt,
                                                      short* __restrict__ Ctx) {
    __shared__ __align__(16) short ldsK[2][64 * 64];
    __shared__ __align__(16) short ldsV[2][64 * 64];
    const int t = threadIdx.x;
    const int w = t >> 6, lane = t & 63;
    const int half = lane >> 5, m = lane & 31;
    const int bh = blockIdx.x;
    const int b = bh / HH, h = bh - b * HH;
    const int q0 = blockIdx.y * 128 + w * 32;

    const short* Qbase = Qb + (size_t)bh * TT * HD;
    const short* Kbase = Kb + (size_t)bh * TT * HD;
    const short* Vbase = Vt + (size_t)bh * HD * TT;

    bf16x8 qf[4];
#pragma unroll
    for (int s = 0; s < 4; s++)
        qf[s] = *(const bf16x8*)&Qbase[(q0 + m) * HD + s * 16 + half * 8];

    int kOff[2], vOff[2];
    {
        int r5 = t >> 3;
        int pi = ((r5 >> 3) & 1) * 16 + ((r5 >> 2) & 1) * 8 + ((r5 >> 4) & 1) * 4 + (r5 & 3);
#pragma unroll
        for (int g = 0; g < 2; g++) {
            kOff[g] = (g * 32 + pi) * 64 + (((t & 7) ^ (r5 & 7)) * 8);
            int vrow = g * 32 + r5;
            vOff[g] = vrow * TT + (((t & 7) ^ (vrow & 7)) * 8);
        }
    }

    auto stage = [&](int buf, int u0) {
#pragma unroll
        for (int g = 0; g < 2; g++)
            gload_lds16(Kbase + (size_t)u0 * 64 + kOff[g], &ldsK[buf][(g * 256 + t) * 8]);
#pragma unroll
        for (int g = 0; g < 2; g++)
            gload_lds16(Vbase + (size_t)u0 + vOff[g], &ldsV[buf][(g * 256 + t) * 8]);
    };

    float16v accO[2];
    accO[0] = (float16v)0.0f;
    accO[1] = (float16v)0.0f;
    float lsum = 0.0f;

    stage(0, 0);

    for (int it = 0; it < TT / 64; ++it) {
        __syncthreads();
        const int buf = it & 1;
        if (it + 1 < TT / 64) stage(buf ^ 1, (it + 1) * 64);
        const short* K_ = &ldsK[buf][0];
        const short* V_ = &ldsV[buf][0];

#pragma unroll
        for (int kt = 0; kt < 2; kt++) {
            float16v st = (float16v)0.0f;
#pragma unroll
            for (int s = 0; s < 4; s++) {
                bf16x8 ka = *(const bf16x8*)&K_[(kt * 32 + m) * 64 + (((s * 2 + half) ^ (m & 7)) * 8)];
                st = __builtin_amdgcn_mfma_f32_32x32x16_bf16(ka, qf[s], st, 0, 0, 0);
            }
            float pe[16];
#pragma unroll
            for (int i = 0; i < 16; i++) pe[i] = __builtin_amdgcn_exp2f(st[i]);
            float s01 = 0.0f;
#pragma unroll
            for (int i = 0; i < 16; i++) s01 += pe[i];
            lsum += s01;
            bf16x8 ap[2];
#pragma unroll
            for (int i = 0; i < 4; i++) {
                ap[0][i]     = (__bf16)pe[i];
                ap[0][4 + i] = (__bf16)pe[8 + i];
                ap[1][i]     = (__bf16)pe[4 + i];
                ap[1][4 + i] = (__bf16)pe[12 + i];
            }
#pragma unroll
            for (int ks = 0; ks < 2; ks++)
#pragma unroll
                for (int dt = 0; dt < 2; dt++) {
                    int row = dt * 32 + m;
                    bf16x8 bv = *(const bf16x8*)&V_[row * 64 + (((kt * 4 + ks * 2 + half) ^ (row & 7)) * 8)];
                    accO[dt] = __builtin_amdgcn_mfma_f32_32x32x16_bf16(ap[ks], bv, accO[dt], 0, 0, 0);
                }
        }
    }

    {
        float v = lsum + __shfl_xor(lsum, 32);
        float linv = 1.0f / v;
#pragma unroll
        for (int s = 0; s < 4; s++)
#pragma unroll
            for (int i = 0; i < 4; i++) {
                int reg = s * 4 + i;
                int qrow = i + s * 8 + half * 4;
                float ln = __shfl(linv, qrow);
                int qg = q0 + qrow;
                size_t base = (size_t)(b * TT + qg) * DOUT + h * HD + m;
                Ctx[base]      = f2bf(accO[0][reg] * ln);
                Ctx[base + 32] = f2bf(accO[1][reg] * ln);
            }
    }
}

// ---- Out GEMM: 64x128 tiles, BK=64 (12 iters), grid 128x6 = 768 blocks ----
__global__ __launch_bounds__(256) void out_gemm_kernel(const short* __restrict__ Cb,
                                                       const short* __restrict__ Wot,
                                                       const float* __restrict__ bo,
                                                       float* __restrict__ out) {
    __shared__ __align__(16) short ldsA[64 * 64];    // 8 KB
    __shared__ __align__(16) short ldsB[128 * 64];   // 16 KB
    const int t = threadIdx.x;
    const int w = t >> 6, lane = t & 63;
    const int quad = lane >> 4, l15 = lane & 15;
    const int m0 = blockIdx.x * 64, n0 = blockIdx.y * 128;
    const int wn = w * 32;

    float4v acc[4][2];
    for (int i = 0; i < 4; i++)
        for (int j = 0; j < 2; j++)
            acc[i][j] = (float4v)0.0f;

    for (int k0 = 0; k0 < DOUT; k0 += 64) {
#pragma unroll
        for (int g = 0; g < 2; g++) {
            int slot = g * 256 + t;
            int row = slot >> 3, ch = slot & 7;
            gload_lds16(Cb + (size_t)(m0 + row) * DOUT + k0 + ((ch ^ (row & 7)) * 8),
                        &ldsA[slot * 8]);
        }
#pragma unroll
        for (int g = 0; g < 4; g++) {
            int slot = g * 256 + t;
            int row = slot >> 3, ch = slot & 7;
            gload_lds16(Wot + (size_t)(n0 + row) * DOUT + k0 + ((ch ^ (row & 7)) * 8),
                        &ldsB[slot * 8]);
        }
        __syncthreads();
#pragma unroll
        for (int f = 0; f < 2; f++) {
            bf16x8 af[4], bfr[2];
            for (int i = 0; i < 4; i++) {
                int row = i * 16 + l15;
                af[i] = *(const bf16x8*)&ldsA[row * 64 + (((f * 4 + quad) ^ (row & 7)) * 8)];
            }
            for (int j = 0; j < 2; j++) {
                int row = wn + j * 16 + l15;
                bfr[j] = *(const bf16x8*)&ldsB[row * 64 + (((f * 4 + quad) ^ (row & 7)) * 8)];
            }
            for (int i = 0; i < 4; i++)
                for (int j = 0; j < 2; j++)
                    acc[i][j] = __builtin_amdgcn_mfma_f32_16x16x32_bf16(af[i], bfr[j], acc[i][j], 0, 0, 0);
        }
        __syncthreads();
    }

    for (int i = 0; i < 4; i++) {
        int m = m0 + i * 16 + quad * 4;
        for (int j = 0; j < 2; j++) {
            int n = n0 + wn + j * 16 + l15;
            float bias = bo[n];
            for (int r = 0; r < 4; r++)
                out[(size_t)(m + r) * DOUT + n] = acc[i][j][r] + bias;
        }
    }
}

extern "C" void kernel_launch(void* const* d_in, const int* in_sizes, int n_in,
                              void* d_out, int out_size, void* d_ws, size_t ws_size,
                              hipStream_t stream) {
    const float* x  = (const float*)d_in[0];
    const float* Wq = (const float*)d_in[1];
    const float* Wk = (const float*)d_in[2];
    const float* Wv = (const float*)d_in[3];
    const float* Wo = (const float*)d_in[4];
    const float* bo = (const float*)d_in[5];
    float* out = (float*)d_out;

    char* ws = (char*)d_ws;
    short* Xb    = (short*)(ws + 0);          // 12582912
    short* Wqkvt = (short*)(ws + 12582912);   //  3538944
    short* Wot   = (short*)(ws + 16121856);   //  1179648
    short* Qb    = (short*)(ws + 17301504);   // 12582912
    short* Kb    = (short*)(ws + 29884416);   // 12582912
    short* Vt    = (short*)(ws + 42467328);   // 12582912
    short* Cb    = (short*)(ws + 55050240);   // 12582912 -> total 67633152 B

    prep_kernel<<<dim3(24, 24, 5), 256, 0, stream>>>(x, Wq, Wk, Wv, Wo, Xb, Wqkvt, Wot);
    qkv_gemm_kernel<<<dim3(MTOT / 128, NQKV / 128), 256, 0, stream>>>(Xb, Wqkvt, Qb, Kb, Vt);
    attn_kernel<<<dim3(BB * HH, TT / 128), 256, 0, stream>>>(Qb, Kb, Vt, Cb);
    out_gemm_kernel<<<dim3(MTOT / 64, DOUT / 128), 256, 0, stream>>>(Cb, Wot, bo, out);
}